// Round 18
// baseline (116.174 us; speedup 1.0000x reference)
//
#include <hip/hip_runtime.h>
#include <stdint.h>

#define NA   3
#define KCH  8       // 5 + NUM_CLASSES
#define BLK  512
#define NWV  (BLK / 64)
#define NB   2048    // stage-1 bins: key16 >> 5
#define MAXN 19200   // 3 * 80 * 80
#define NH   9600    // s0 half-row
#define QCAP 512
#define LKEY 0xBFA8u // raw-obj key16 rung (~obj>1.31, ~9.5% of N(0,1)); runtime-verified

#define LOG2E 1.4426950408889634f
#define LN2   0.6931471805599453f

struct ScaleParams {
  const float*   pred;    // (B, 24, H, W)
  const float*   boxes;   // (B, N, 4)
  const int*     labels;  // (B, N)
  const uint8_t* pos;     // (B, N) bool
  const uint8_t* neg;     // (B, N) bool
  int HW;
};

__device__ __forceinline__ float fexp2(float x) { return __builtin_amdgcn_exp2f(x); }
__device__ __forceinline__ float flog2(float x) { return __builtin_amdgcn_logf(x); }

__device__ __forceinline__ float softplus_fast(float x) {
  const float t = fexp2(-fabsf(x) * LOG2E);
  return fmaxf(x, 0.f) + flog2(1.f + t) * LN2;
}

__device__ __forceinline__ float sl1f(float d) {
  float ad = fabsf(d);
  return (ad < 1.f) ? 0.5f * d * d : ad - 0.5f;
}

// order-preserving float->uint key (larger float => larger key)
__device__ __forceinline__ unsigned fkey(unsigned u) {
  return (u & 0x80000000u) ? ~u : (u | 0x80000000u);
}
__device__ __forceinline__ unsigned funkey(unsigned k) {
  return (k & 0x80000000u) ? (k & 0x7FFFFFFFu) : ~k;
}
// reconstruct approx obj from 16-bit key (midpoint), then softplus
__device__ __forceinline__ float sp16(unsigned k16) {
  return softplus_fast(__uint_as_float(funkey((k16 << 16) | 0x8000u)));
}

struct __align__(16) RowShared {
  unsigned short keys[MAXN];   // 38.4 KB (0 = not-neg)
  unsigned hc[NB];             // 8 KB counts (keys > Lcur)
  float    hs[NB];             // 8 KB value-sums (same filter)
  int      queue[QCAP];
  int      sh_qn;
  int      iwav[NWV];
  float    fwav[NWV];
  float    fscr[NWV];
  float    wred[NWV][5];
  int      sh_dig, sh_krem;
  float    sh_sa, sh_avg;
  int      sh_flag;
  unsigned c32[32];
  float    s32[32];
};

__device__ __forceinline__ float blockSum(float v, float* scr) {
  #pragma unroll
  for (int off = 32; off > 0; off >>= 1) v += __shfl_down(v, off);
  const int lane = threadIdx.x & 63, w = threadIdx.x >> 6;
  __syncthreads();
  if (lane == 0) scr[w] = v;
  __syncthreads();
  float r = 0.f;
  #pragma unroll
  for (int i = 0; i < NWV; ++i) r += scr[i];
  return r;
}

// counts+sums suffix select over NB bins, 4 bins/thread. Block-uniform.
__device__ __forceinline__ void selectDigit4(const unsigned* cb, const float* sb,
    int krem_in, float sa_in, RowShared& S) {
  const int t = threadIdx.x, lane = t & 63, w = t >> 6;
  int c_t = 0; float s_t = 0.f;
  #pragma unroll
  for (int q = 0; q < 4; ++q) { c_t += (int)cb[q]; s_t += sb[q]; }
  int ci = c_t; float si = s_t;          // wave inclusive suffix scan
  #pragma unroll
  for (int off = 1; off < 64; off <<= 1) {
    const int   co = __shfl_down(ci, off);
    const float so = __shfl_down(si, off);
    if (lane + off < 64) { ci += co; si += so; }
  }
  __syncthreads();
  if (lane == 0) { S.iwav[w] = ci; S.fwav[w] = si; }
  __syncthreads();
  int ac = 0; float as = 0.f;
  #pragma unroll
  for (int w2 = 0; w2 < NWV; ++w2)
    if (w2 > w) { ac += S.iwav[w2]; as += S.fwav[w2]; }
  int   cum_c = (ci - c_t) + ac;
  float cum_s = (si - s_t) + as;
  #pragma unroll
  for (int q = 3; q >= 0; --q) {
    const int cq = (int)cb[q];
    if (cq > 0 && cum_c < krem_in && krem_in <= cum_c + cq) {
      S.sh_dig  = t * 4 + q;
      S.sh_krem = krem_in - cum_c;
      S.sh_sa   = sa_in + cum_s;
    }
    cum_c += cq; cum_s += sb[q];
  }
  __syncthreads();
}

// Sweep a slice [c0, c0+NLOC) of row b: keys -> LDS[0..NLOC), filtered
// (count,sum) hist, pos queue + dense pos work. Returns npos; red[5] totals.
template<int HW, int NLOC>
__device__ __forceinline__ int scan_slice(
    const ScaleParams& P, int b, int c0, RowShared& S, float red[5]) {
  constexpr int N = 3 * HW;
  constexpr int ITER = (NLOC + BLK * 8 - 1) / (BLK * 8);
  const int t = threadIdx.x;

  for (int i = t; i < NB; i += BLK) { S.hc[i] = 0u; S.hs[i] = 0.f; }
  if (t == 0) S.sh_qn = 0;
  __syncthreads();

  const float* predb = P.pred + (size_t)b * (NA * KCH) * HW;
  const size_t row = (size_t)b * N;
  float nneg = 0.f; int above = 0;

  float4 o0[ITER], o1[ITER];
  uint2  pmv[ITER], nmv[ITER];
  #pragma unroll
  for (int it = 0; it < ITER; ++it) {
    const int c8 = c0 + it * (BLK * 8) + t * 8;
    if (c8 < c0 + NLOC) {
      const int a = (c8 >= HW) + (c8 >= 2 * HW);
      const int cell = c8 - a * HW;
      const float* po = predb + (size_t)a * KCH * HW + 4 * HW + cell;
      o0[it]  = *(const float4*)po;
      o1[it]  = *(const float4*)(po + 4);
      pmv[it] = *(const uint2*)(P.pos + row + c8);
      nmv[it] = *(const uint2*)(P.neg + row + c8);
    }
  }
  #pragma unroll
  for (int it = 0; it < ITER; ++it) {
    const int c8 = c0 + it * (BLK * 8) + t * 8;
    if (c8 < c0 + NLOC) {
      const unsigned long long nm64 =
          ((unsigned long long)nmv[it].y << 32) | nmv[it].x;
      nneg += (float)__popcll(nm64);
      unsigned kk[8];
      #pragma unroll
      for (int q = 0; q < 8; ++q) {
        const float obj = (q < 4) ? (&o0[it].x)[q] : (&o1[it].x)[q - 4];
        const unsigned nm = ((q < 4) ? (nmv[it].x >> (8 * q))
                                     : (nmv[it].y >> (8 * (q - 4)))) & 0xFFu;
        const unsigned pm = ((q < 4) ? (pmv[it].x >> (8 * q))
                                     : (pmv[it].y >> (8 * (q - 4)))) & 0xFFu;
        unsigned k16 = 0u;
        if (nm) {
          k16 = fkey(__float_as_uint(obj)) >> 16;
          if (k16 > LKEY) {
            ++above;
            atomicAdd(&S.hc[k16 >> 5], 1u);
            atomicAdd(&S.hs[k16 >> 5], sp16(k16));
          }
        }
        kk[q] = k16;
        if (pm) {
          const int idx = atomicAdd(&S.sh_qn, 1);
          if (idx < QCAP) S.queue[idx] = c8 + q;
        }
      }
      uint4 kv;
      kv.x = kk[0] | (kk[1] << 16); kv.y = kk[2] | (kk[3] << 16);
      kv.z = kk[4] | (kk[5] << 16); kv.w = kk[6] | (kk[7] << 16);
      *reinterpret_cast<uint4*>(&S.keys[c8 - c0]) = kv;
    }
  }
  __syncthreads();
  const int npos = S.sh_qn;
  const int qn = min(npos, QCAP);

  float posobj = 0.f, ce = 0.f, loc = 0.f;
  for (int i = t; i < qn; i += BLK) {
    const int j = S.queue[i];
    const int a = (j >= HW) + (j >= 2 * HW);
    const int cell = j - a * HW;
    const float* pa = predb + (size_t)a * KCH * HW;
    posobj += softplus_fast(-pa[4 * HW + cell]);     // sp(x)-x == sp(-x)
    const float c0f = pa[5 * HW + cell];
    const float c1f = pa[6 * HW + cell];
    const float c2f = pa[7 * HW + cell];
    const float m = fmaxf(fmaxf(c0f, c1f), c2f);
    const float e = fexp2((c0f - m) * LOG2E) + fexp2((c1f - m) * LOG2E)
                  + fexp2((c2f - m) * LOG2E);
    const float lse = m + flog2(e) * LN2;
    const int lab = P.labels[row + j];
    ce += lse - ((lab == 0) ? c0f : (lab == 1) ? c1f : c2f);
    const float4 bx = *(const float4*)(P.boxes + (size_t)(row + j) * 4);
    loc += sl1f(pa[0 * HW + cell] - bx.x) + sl1f(pa[1 * HW + cell] - bx.y)
         + sl1f(pa[2 * HW + cell] - bx.z) + sl1f(pa[3 * HW + cell] - bx.w);
  }

  {
    float v[5] = {nneg, posobj, ce, loc, (float)above};
    #pragma unroll
    for (int i = 0; i < 5; ++i) {
      #pragma unroll
      for (int off = 32; off > 0; off >>= 1) v[i] += __shfl_down(v[i], off);
    }
    const int lane = t & 63, w = t >> 6;
    __syncthreads();
    if (lane == 0) {
      #pragma unroll
      for (int i = 0; i < 5; ++i) S.wred[w][i] = v[i];
    }
    __syncthreads();
  }
  #pragma unroll
  for (int i = 0; i < 5; ++i) {
    float acc = 0.f;
    #pragma unroll
    for (int w2 = 0; w2 < NWV; ++w2) acc += S.wred[w2][i];
    red[i] = acc;
  }
  return npos;
}

// Select top-k sum given merged (count,sum) hist + nk keys in S.keys.
__device__ __forceinline__ float select_refine(int k, int above, int nk,
                                               RowShared& S) {
  const int t = threadIdx.x;
  unsigned Lcur = LKEY;
  if (above < k) {     // rare exact fallback: complete hist for keys <= LKEY
    for (int c8 = t * 8; c8 < nk; c8 += BLK * 8) {
      const uint4 kv = reinterpret_cast<const uint4*>(S.keys)[c8 >> 3];
      const unsigned ks[8] = {kv.x & 0xFFFFu, kv.x >> 16, kv.y & 0xFFFFu,
                              kv.y >> 16,     kv.z & 0xFFFFu, kv.z >> 16,
                              kv.w & 0xFFFFu, kv.w >> 16};
      #pragma unroll
      for (int q = 0; q < 8; ++q)
        if (ks[q] && ks[q] <= LKEY) {
          atomicAdd(&S.hc[ks[q] >> 5], 1u);
          atomicAdd(&S.hs[ks[q] >> 5], sp16(ks[q]));
        }
    }
    __syncthreads();
    Lcur = 0u;
  }

  unsigned cb[4]; float sb[4];
  #pragma unroll
  for (int q = 0; q < 4; ++q) { cb[q] = S.hc[4 * t + q]; sb[q] = S.hs[4 * t + q]; }
  selectDigit4(cb, sb, k, 0.f, S);
  const int bin1 = S.sh_dig; const int krem1 = S.sh_krem;
  const float sa1 = S.sh_sa;                 // exact sum above bin1 (from hs)

  if (t < 32) { S.c32[t] = 0u; S.s32[t] = 0.f; }
  __syncthreads();

  for (int c8 = t * 8; c8 < nk; c8 += BLK * 8) {   // refine inside bin1 only
    const uint4 kv = reinterpret_cast<const uint4*>(S.keys)[c8 >> 3];
    const unsigned ks[8] = {kv.x & 0xFFFFu, kv.x >> 16, kv.y & 0xFFFFu,
                            kv.y >> 16,     kv.z & 0xFFFFu, kv.z >> 16,
                            kv.w & 0xFFFFu, kv.w >> 16};
    #pragma unroll
    for (int q = 0; q < 8; ++q) {
      const unsigned k16 = ks[q];
      if (k16 > Lcur && (int)(k16 >> 5) == bin1) {
        atomicAdd(&S.c32[k16 & 31u], 1u);
        atomicAdd(&S.s32[k16 & 31u], sp16(k16));
      }
    }
  }
  __syncthreads();

  if (t < 64) {
    const int cc = (t < 32) ? (int)S.c32[t] : 0;
    const float ss = (t < 32) ? S.s32[t] : 0.f;
    int ci = cc; float si = ss;
    #pragma unroll
    for (int off = 1; off < 64; off <<= 1) {
      const int   co = __shfl_down(ci, off);
      const float so = __shfl_down(si, off);
      if ((t & 63) + off < 64) { ci += co; si += so; }
    }
    const int   above_c = ci - cc;
    const float above_s = si - ss;
    if (t < 32 && cc > 0 && above_c < krem1 && krem1 <= above_c + cc) {
      S.sh_krem = krem1 - above_c;
      S.sh_sa   = sa1 + above_s;
      S.sh_avg  = ss / (float)cc;            // tie-bin average (key-exact)
    }
  }
  __syncthreads();
  return S.sh_sa + (float)S.sh_krem * S.sh_avg;
}

template<int HW>
__device__ __forceinline__ void row_whole(const ScaleParams& P, int b,
                                          float* part, RowShared& S) {
  constexpr int N = 3 * HW;
  float red[5];
  const int npos = scan_slice<HW, N>(P, b, 0, S, red);
  const int k = min(3 * npos, (int)red[0]);
  float sel = 0.f;
  if (k > 0) sel = select_refine(k, (int)red[4], N, S);
  if (threadIdx.x == 0) {
    const float denom = (float)max(npos, 1);
    part[0] = (red[1] + sel) / denom;
    part[1] = (npos > 0) ? red[2] / denom : 0.f;
    part[2] = (npos > 0) ? red[3] / (denom * 4.f) : 0.f;
  }
}

// s0 half: scan, publish (plain stores), per-row ticket; last half merges
// sibling's keys+hist in LDS and finishes the row. Returns true if finisher.
__device__ __forceinline__ bool row_s0_half(
    const ScaleParams& p0, int b, int half,
    unsigned short* g_keys, unsigned* g_hc, float* g_hs, float* g_scal,
    unsigned* g_tick, float* part, RowShared& S) {
  constexpr int HW = 6400;
  float red[5];
  const int npos = scan_slice<HW, NH>(p0, b, half * NH, S, red);
  const int t = threadIdx.x;

  const size_t hid = (size_t)b * 2 + half;
  {
    uint4* gk = (uint4*)(g_keys + hid * NH);
    const uint4* lk = reinterpret_cast<const uint4*>(S.keys);
    for (int i = t; i < NH / 8; i += BLK) gk[i] = lk[i];     // 19.2 KB
    unsigned* ghc = g_hc + hid * NB; float* ghs = g_hs + hid * NB;
    for (int i = t; i < NB; i += BLK) { ghc[i] = S.hc[i]; ghs[i] = S.hs[i]; }
    if (t == 0) {
      float* gs = g_scal + hid * 8;
      gs[0] = (float)npos; gs[1] = red[0]; gs[2] = red[1];
      gs[3] = red[2]; gs[4] = red[3]; gs[5] = red[4];
    }
  }
  __threadfence();                      // each thread releases its own stores
  __syncthreads();
  if (t == 0) {
    const unsigned old = atomicAdd(&g_tick[b], 1u);
    S.sh_flag = (old == 1u) ? 1 : 0;
  }
  __syncthreads();
  if (!S.sh_flag) return false;
  __threadfence();                      // acquire sibling's stores

  const size_t oid = (size_t)b * 2 + (half ^ 1);
  {
    const uint4* gk = (const uint4*)(g_keys + oid * NH);
    uint4* lk = reinterpret_cast<uint4*>(S.keys + NH);
    for (int i = t; i < NH / 8; i += BLK) lk[i] = gk[i];     // sibling keys
    const unsigned* ghc = g_hc + oid * NB; const float* ghs = g_hs + oid * NB;
    for (int i = t; i < NB; i += BLK) { S.hc[i] += ghc[i]; S.hs[i] += ghs[i]; }
  }
  const float* gs = g_scal + oid * 8;
  const int   npos_t = npos + (int)gs[0];
  const float nneg_t = red[0] + gs[1];
  const float po_t   = red[1] + gs[2];
  const float ce_t   = red[2] + gs[3];
  const float lc_t   = red[3] + gs[4];
  const int   abv_t  = (int)(red[4] + gs[5]);
  __syncthreads();

  const int k = min(3 * npos_t, (int)nneg_t);
  float sel = 0.f;
  if (k > 0) sel = select_refine(k, abv_t, MAXN, S);
  if (t == 0) {
    const float denom = (float)max(npos_t, 1);
    part[0] = (po_t + sel) / denom;
    part[1] = (npos_t > 0) ? ce_t / denom : 0.f;
    part[2] = (npos_t > 0) ? lc_t / (denom * 4.f) : 0.f;
  }
  return true;
}

__global__ void k_zero(unsigned* g_tick, int B, unsigned* done) {
  for (int i = threadIdx.x; i < B; i += blockDim.x) g_tick[i] = 0u;
  if (threadIdx.x == 0) *done = 0u;
}

__global__ __launch_bounds__(BLK) void k_row(
    ScaleParams p0, ScaleParams p1, ScaleParams p2, int B, int R, float invB,
    unsigned short* g_keys, unsigned* g_hc, float* g_hs, float* g_scal,
    unsigned* g_tick, float* g_part, unsigned* done, float* out) {
  __shared__ RowShared S;
  const int bid = blockIdx.x;
  bool emit = true;
  if (bid < 2 * B) {
    const int b = bid >> 1, half = bid & 1;
    emit = row_s0_half(p0, b, half, g_keys, g_hc, g_hs, g_scal, g_tick,
                       g_part + (size_t)b * 4, S);
  } else if (bid < 3 * B) {
    const int b = bid - 2 * B;
    row_whole<1600>(p1, b, g_part + (size_t)(B + b) * 4, S);
  } else {
    const int b = bid - 3 * B;
    row_whole<400>(p2, b, g_part + (size_t)(2 * B + b) * 4, S);
  }
  if (!emit) return;

  if (threadIdx.x == 0) {
    __threadfence();
    const unsigned old = atomicAdd(done, 1u);
    S.sh_flag = (old == (unsigned)(R - 1)) ? 1 : 0;
  }
  __syncthreads();
  if (S.sh_flag) {
    __threadfence();
    const int t = threadIdx.x;
    float o = 0.f, c = 0.f, l = 0.f;
    for (int i = t; i < R; i += BLK) {
      o += g_part[i * 4 + 0];
      c += g_part[i * 4 + 1];
      l += g_part[i * 4 + 2];
    }
    o = blockSum(o, S.fscr);
    c = blockSum(c, S.fscr);
    l = blockSum(l, S.fscr);
    if (t == 0) {
      out[0] = (o + c + l) * invB;
      out[1] = o * invB;
      out[2] = c * invB;
      out[3] = l * invB;
    }
  }
}

extern "C" void kernel_launch(void* const* d_in, const int* in_sizes, int n_in,
                              void* d_out, int out_size, void* d_ws, size_t ws_size,
                              hipStream_t stream) {
  (void)n_in; (void)out_size; (void)ws_size;

  const int HW0 = 80 * 80, HW1 = 40 * 40, HW2 = 20 * 20;
  const int B = in_sizes[0] / (NA * KCH * HW0);
  const int R = 3 * B;
  const float invB = 1.f / (float)B;

  ScaleParams p0{(const float*)d_in[0],  (const float*)d_in[1],
                 (const int*)d_in[2],    (const uint8_t*)d_in[3],
                 (const uint8_t*)d_in[4], HW0};
  ScaleParams p1{(const float*)d_in[5],  (const float*)d_in[6],
                 (const int*)d_in[7],    (const uint8_t*)d_in[8],
                 (const uint8_t*)d_in[9], HW1};
  ScaleParams p2{(const float*)d_in[10], (const float*)d_in[11],
                 (const int*)d_in[12],   (const uint8_t*)d_in[13],
                 (const uint8_t*)d_in[14], HW2};

  float* out = (float*)d_out;

  // workspace layout (256B-aligned sections); ws ~314 MB per harness fills
  char* w = (char*)d_ws;
  unsigned*       done   = (unsigned*)w;        w += 256;
  unsigned*       g_tick = (unsigned*)w;        w += (((size_t)B * 4 + 255) & ~255ull);
  float*          g_part = (float*)w;           w += (((size_t)R * 16 + 255) & ~255ull);
  float*          g_scal = (float*)w;           w += (((size_t)B * 2 * 8 * 4 + 255) & ~255ull);
  unsigned*       g_hc   = (unsigned*)w;        w += (size_t)B * 2 * NB * 4;
  float*          g_hs   = (float*)w;           w += (size_t)B * 2 * NB * 4;
  unsigned short* g_keys = (unsigned short*)w;  w += (size_t)B * 2 * NH * 2;

  k_zero<<<1, 256, 0, stream>>>(g_tick, B, done);
  k_row<<<4 * B, BLK, 0, stream>>>(p0, p1, p2, B, R, invB,
                                   g_keys, g_hc, g_hs, g_scal,
                                   g_tick, g_part, done, out);
}

// Round 19
// 28.737 us; speedup vs baseline: 4.0427x; 4.0427x over previous
//
#include <hip/hip_runtime.h>
#include <stdint.h>

#define NA   3
#define KCH  8       // 5 + NUM_CLASSES
#define BLK  512
#define NWV  (BLK / 64)
#define NB   2048    // stage-1 bins: key16 >> 5
#define QCAP 512
#define CCAP 4096    // compact candidate capacity (~9.5% of 19200 = 1824 avg)
#define LKEY 0xBFA8u // raw-obj key16 rung (obj>1.3125, ~9.5% of N(0,1)); runtime-verified

#define LOG2E 1.4426950408889634f
#define LN2   0.6931471805599453f

struct ScaleParams {
  const float*   pred;    // (B, 24, H, W)
  const float*   boxes;   // (B, N, 4)
  const int*     labels;  // (B, N)
  const uint8_t* pos;     // (B, N) bool
  const uint8_t* neg;     // (B, N) bool
  int HW;
};

__device__ __forceinline__ float fexp2(float x) { return __builtin_amdgcn_exp2f(x); }
__device__ __forceinline__ float flog2(float x) { return __builtin_amdgcn_logf(x); }

// logaddexp(0,x) = max(x,0) + log1p(exp(-|x|)); native exp2/log2, ~1e-6 rel
__device__ __forceinline__ float softplus_fast(float x) {
  const float t = fexp2(-fabsf(x) * LOG2E);
  return fmaxf(x, 0.f) + flog2(1.f + t) * LN2;
}

__device__ __forceinline__ float sl1f(float d) {
  float ad = fabsf(d);
  return (ad < 1.f) ? 0.5f * d * d : ad - 0.5f;
}

// order-preserving float->uint key (larger float => larger key)
__device__ __forceinline__ unsigned fkey(unsigned u) {
  return (u & 0x80000000u) ? ~u : (u | 0x80000000u);
}
__device__ __forceinline__ unsigned funkey(unsigned k) {
  return (k & 0x80000000u) ? (k & 0x7FFFFFFFu) : ~k;
}
// softplus of obj reconstructed from 16-bit key (interval midpoint)
__device__ __forceinline__ float sp16(unsigned k16) {
  return softplus_fast(__uint_as_float(funkey((k16 << 16) | 0x8000u)));
}

struct __align__(16) RowShared {
  unsigned short compact[CCAP];  // 8 KB: keys > LKEY
  unsigned hc[NB];               // 8 KB: counts (keys > LKEY unless fallback)
  float    hs[NB];               // 8 KB: sp16 sums (same filter)
  int      queue[QCAP];          // 2 KB: pos-anchor indices
  int      sh_qn, sh_nc;
  int      iwav[NWV];
  float    fwav[NWV];
  float    fscr[NWV];
  float    wred[NWV][4];
  int      sh_dig, sh_krem;
  float    sh_sa, sh_avg;
  int      sh_flag;
  unsigned c32[32];
  float    s32[32];
};

__device__ __forceinline__ float blockSum(float v, float* scr) {
  #pragma unroll
  for (int off = 32; off > 0; off >>= 1) v += __shfl_down(v, off);
  const int lane = threadIdx.x & 63, w = threadIdx.x >> 6;
  __syncthreads();
  if (lane == 0) scr[w] = v;
  __syncthreads();
  float r = 0.f;
  #pragma unroll
  for (int i = 0; i < NWV; ++i) r += scr[i];
  return r;
}

// counts+sums suffix select over NB bins, 4 bins/thread. Block-uniform.
// Finds bin of the krem-th LARGEST, remaining count, exact sum above it.
__device__ __forceinline__ void selectDigit4(const unsigned* cb, const float* sb,
                                             int krem_in, RowShared& S) {
  const int t = threadIdx.x, lane = t & 63, w = t >> 6;
  int c_t = 0; float s_t = 0.f;
  #pragma unroll
  for (int q = 0; q < 4; ++q) { c_t += (int)cb[q]; s_t += sb[q]; }
  int ci = c_t; float si = s_t;          // wave inclusive suffix scan
  #pragma unroll
  for (int off = 1; off < 64; off <<= 1) {
    const int   co = __shfl_down(ci, off);
    const float so = __shfl_down(si, off);
    if (lane + off < 64) { ci += co; si += so; }
  }
  __syncthreads();
  if (lane == 0) { S.iwav[w] = ci; S.fwav[w] = si; }
  __syncthreads();
  int ac = 0; float as = 0.f;
  #pragma unroll
  for (int w2 = 0; w2 < NWV; ++w2)
    if (w2 > w) { ac += S.iwav[w2]; as += S.fwav[w2]; }
  int   cum_c = (ci - c_t) + ac;
  float cum_s = (si - s_t) + as;
  #pragma unroll
  for (int q = 3; q >= 0; --q) {
    const int cq = (int)cb[q];
    if (cq > 0 && cum_c < krem_in && krem_in <= cum_c + cq) {
      S.sh_dig  = t * 4 + q;
      S.sh_krem = krem_in - cum_c;
      S.sh_sa   = cum_s;
    }
    cum_c += cq; cum_s += sb[q];
  }
  __syncthreads();
}

// Rare path A: complete the histogram with keys <= LKEY (global re-read, L2-warm).
template<int HW>
__device__ void hist_low(const ScaleParams& P, int b, RowShared& S) {
  constexpr int N = 3 * HW;
  const float* predb = P.pred + (size_t)b * (NA * KCH) * HW;
  const size_t row = (size_t)b * N;
  for (int c8 = threadIdx.x * 8; c8 < N; c8 += BLK * 8) {
    const int a = (c8 >= HW) + (c8 >= 2 * HW);
    const int cell = c8 - a * HW;
    const float* po = predb + (size_t)a * KCH * HW + 4 * HW + cell;
    const float4 o0 = *(const float4*)po;
    const float4 o1 = *(const float4*)(po + 4);
    const uint2 nmv = *(const uint2*)(P.neg + row + c8);
    #pragma unroll
    for (int q = 0; q < 8; ++q) {
      const unsigned nm = ((q < 4) ? (nmv.x >> (8 * q))
                                   : (nmv.y >> (8 * (q - 4)))) & 0xFFu;
      if (nm) {
        const float obj = (q < 4) ? (&o0.x)[q] : (&o1.x)[q - 4];
        const unsigned k16 = fkey(__float_as_uint(obj)) >> 16;
        if (k16 <= LKEY) {
          atomicAdd(&S.hc[k16 >> 5], 1u);
          atomicAdd(&S.hs[k16 >> 5], sp16(k16));
        }
      }
    }
  }
}

// Rare path B: refine bin1 from a global re-read (lmin filter matches hist).
template<int HW>
__device__ void refine_global(const ScaleParams& P, int b, int bin1,
                              unsigned lmin, RowShared& S) {
  constexpr int N = 3 * HW;
  const float* predb = P.pred + (size_t)b * (NA * KCH) * HW;
  const size_t row = (size_t)b * N;
  for (int c8 = threadIdx.x * 8; c8 < N; c8 += BLK * 8) {
    const int a = (c8 >= HW) + (c8 >= 2 * HW);
    const int cell = c8 - a * HW;
    const float* po = predb + (size_t)a * KCH * HW + 4 * HW + cell;
    const float4 o0 = *(const float4*)po;
    const float4 o1 = *(const float4*)(po + 4);
    const uint2 nmv = *(const uint2*)(P.neg + row + c8);
    #pragma unroll
    for (int q = 0; q < 8; ++q) {
      const unsigned nm = ((q < 4) ? (nmv.x >> (8 * q))
                                   : (nmv.y >> (8 * (q - 4)))) & 0xFFu;
      if (nm) {
        const float obj = (q < 4) ? (&o0.x)[q] : (&o1.x)[q - 4];
        const unsigned k16 = fkey(__float_as_uint(obj)) >> 16;
        if (k16 > lmin && (int)(k16 >> 5) == bin1) {
          atomicAdd(&S.c32[k16 & 31u], 1u);
          atomicAdd(&S.s32[k16 & 31u], sp16(k16));
        }
      }
    }
  }
}

// Whole-row processing, compile-time N. Round-16 shell; keys[] replaced by a
// compact >LKEY candidate list + (count,sum) histogram carried in sweep 1.
template<int HW>
__device__ __forceinline__ void row_impl(
    const ScaleParams P, int b, float* part, RowShared& S) {
  constexpr int N = 3 * HW;
  constexpr int ITER = (N + BLK * 8 - 1) / (BLK * 8);
  const int t = threadIdx.x;

  for (int i = t; i < NB; i += BLK) { S.hc[i] = 0u; S.hs[i] = 0.f; }
  if (t == 0) { S.sh_qn = 0; S.sh_nc = 0; }
  __syncthreads();

  const float* predb = P.pred + (size_t)b * (NA * KCH) * HW;
  const size_t row = (size_t)b * N;
  float nneg = 0.f;

  // ---- sweep 1, phase A: issue ALL global loads (compile-time unroll) ----
  float4 o0[ITER], o1[ITER];
  uint2  pmv[ITER], nmv[ITER];
  #pragma unroll
  for (int it = 0; it < ITER; ++it) {
    const int c8 = it * (BLK * 8) + t * 8;
    if (c8 < N) {
      const int a = (c8 >= HW) + (c8 >= 2 * HW);
      const int cell = c8 - a * HW;
      const float* po = predb + (size_t)a * KCH * HW + 4 * HW + cell;
      o0[it]  = *(const float4*)po;
      o1[it]  = *(const float4*)(po + 4);
      pmv[it] = *(const uint2*)(P.pos + row + c8);
      nmv[it] = *(const uint2*)(P.neg + row + c8);
    }
  }

  // ---- sweep 1, phase B: compact >LKEY keys + (count,sum) hist + queue ----
  #pragma unroll
  for (int it = 0; it < ITER; ++it) {
    const int c8 = it * (BLK * 8) + t * 8;
    if (c8 < N) {
      const unsigned long long nm64 =
          ((unsigned long long)nmv[it].y << 32) | nmv[it].x;
      nneg += (float)__popcll(nm64);       // bool bytes are 0/1
      #pragma unroll
      for (int q = 0; q < 8; ++q) {
        const unsigned nm = ((q < 4) ? (nmv[it].x >> (8 * q))
                                     : (nmv[it].y >> (8 * (q - 4)))) & 0xFFu;
        const unsigned pm = ((q < 4) ? (pmv[it].x >> (8 * q))
                                     : (pmv[it].y >> (8 * (q - 4)))) & 0xFFu;
        if (nm) {
          const float obj = (q < 4) ? (&o0[it].x)[q] : (&o1[it].x)[q - 4];
          const unsigned k16 = fkey(__float_as_uint(obj)) >> 16;
          if (k16 > LKEY) {                // ~9.5% of negs
            const int ci = atomicAdd(&S.sh_nc, 1);
            if (ci < CCAP) S.compact[ci] = (unsigned short)k16;
            atomicAdd(&S.hc[k16 >> 5], 1u);
            atomicAdd(&S.hs[k16 >> 5], sp16(k16));
          }
        }
        if (pm) {
          const int idx = atomicAdd(&S.sh_qn, 1);
          if (idx < QCAP) S.queue[idx] = c8 + q;
        }
      }
    }
  }
  __syncthreads();
  const int npos = S.sh_qn;
  const int nc   = S.sh_nc;              // exact count of keys > LKEY
  const int qn = min(npos, QCAP);

  // ---- dense pos-anchor work (~1%): softplus/CE/smooth-L1, L2-hot ----
  float posobj = 0.f, ce = 0.f, loc = 0.f;
  for (int i = t; i < qn; i += BLK) {
    const int j = S.queue[i];
    const int a = (j >= HW) + (j >= 2 * HW);
    const int cell = j - a * HW;
    const float* pa = predb + (size_t)a * KCH * HW;
    posobj += softplus_fast(-pa[4 * HW + cell]);     // sp(x)-x == sp(-x)
    const float c0f = pa[5 * HW + cell];
    const float c1f = pa[6 * HW + cell];
    const float c2f = pa[7 * HW + cell];
    const float m = fmaxf(fmaxf(c0f, c1f), c2f);
    const float e = fexp2((c0f - m) * LOG2E) + fexp2((c1f - m) * LOG2E)
                  + fexp2((c2f - m) * LOG2E);
    const float lse = m + flog2(e) * LN2;
    const int lab = P.labels[row + j];
    ce += lse - ((lab == 0) ? c0f : (lab == 1) ? c1f : c2f);
    const float4 bx = *(const float4*)(P.boxes + (size_t)(row + j) * 4);
    loc += sl1f(pa[0 * HW + cell] - bx.x) + sl1f(pa[1 * HW + cell] - bx.y)
         + sl1f(pa[2 * HW + cell] - bx.z) + sl1f(pa[3 * HW + cell] - bx.w);
  }

  // ---- packed block reduction of 4 scalars (one barrier round) ----
  {
    float v[4] = {nneg, posobj, ce, loc};
    #pragma unroll
    for (int i = 0; i < 4; ++i) {
      #pragma unroll
      for (int off = 32; off > 0; off >>= 1) v[i] += __shfl_down(v[i], off);
    }
    const int lane = t & 63, w = t >> 6;
    __syncthreads();
    if (lane == 0) {
      #pragma unroll
      for (int i = 0; i < 4; ++i) S.wred[w][i] = v[i];
    }
    __syncthreads();
  }
  float red[4];
  #pragma unroll
  for (int i = 0; i < 4; ++i) {
    float acc = 0.f;
    #pragma unroll
    for (int w2 = 0; w2 < NWV; ++w2) acc += S.wred[w2][i];
    red[i] = acc;
  }
  const float t_po = red[1], t_ce = red[2], t_lc = red[3];
  const int k = min(3 * npos, (int)red[0]);

  float sel = 0.f;
  if (k > 0) {  // block-uniform
    unsigned lmin = LKEY;
    const bool fell = (nc < k);
    if (fell) {           // rare exact fallback: add keys <= LKEY to hist
      hist_low<HW>(P, b, S);
      __syncthreads();
      lmin = 0u;
    }

    // ---- stage 1: 2048 bins (counts+sums) -> bin1, krem1, exact sa1 ----
    unsigned cb[4]; float sb[4];
    #pragma unroll
    for (int q = 0; q < 4; ++q) { cb[q] = S.hc[4*t+q]; sb[q] = S.hs[4*t+q]; }
    selectDigit4(cb, sb, k, S);
    const int bin1 = S.sh_dig; const int krem1 = S.sh_krem;
    const float sa1 = S.sh_sa;           // exact sum above bin1 (from hs)

    if (t < 32) { S.c32[t] = 0u; S.s32[t] = 0.f; }
    __syncthreads();

    // ---- refine bin1 into 32 sub-bins ----
    if (!fell && nc <= CCAP) {
      for (int i = t; i < nc; i += BLK) {      // ~1800 entries: 6x shorter
        const unsigned k16 = S.compact[i];
        if ((int)(k16 >> 5) == bin1) {
          atomicAdd(&S.c32[k16 & 31u], 1u);
          atomicAdd(&S.s32[k16 & 31u], sp16(k16));
        }
      }
    } else {
      refine_global<HW>(P, b, bin1, lmin, S);  // rare: overflow or fallback
    }
    __syncthreads();

    // ---- stage 2: 32 sub-bins, one wave (lanes >=32 carry zeros) ----
    if (t < 64) {
      const int cc = (t < 32) ? (int)S.c32[t] : 0;
      const float ss = (t < 32) ? S.s32[t] : 0.f;
      int ci = cc; float si = ss;
      #pragma unroll
      for (int off = 1; off < 64; off <<= 1) {
        const int   co = __shfl_down(ci, off);
        const float so = __shfl_down(si, off);
        if ((t & 63) + off < 64) { ci += co; si += so; }
      }
      const int   above_c = ci - cc;
      const float above_s = si - ss;
      if (t < 32 && cc > 0 && above_c < krem1 && krem1 <= above_c + cc) {
        S.sh_krem = krem1 - above_c;
        S.sh_sa   = sa1 + above_s;
        S.sh_avg  = ss / (float)cc;      // all entries share key16: exact
      }
    }
    __syncthreads();
    sel = S.sh_sa + (float)S.sh_krem * S.sh_avg;
  }

  if (t == 0) {
    const float denom = (float)max(npos, 1);
    part[0] = (t_po + sel) / denom;                     // plain stores
    part[1] = (npos > 0) ? t_ce / denom : 0.f;
    part[2] = (npos > 0) ? t_lc / (denom * 4.f) : 0.f;
  }
}

__global__ void k_zero(unsigned* done) {
  if (threadIdx.x == 0) *done = 0u;
}

// One block per (scale, batch) row; last-arriving block reduces g_part -> out.
__global__ __launch_bounds__(BLK) void k_row(
    ScaleParams p0, ScaleParams p1, ScaleParams p2,
    int B, int R, float invB, float* g_part, unsigned* done, float* out) {
  __shared__ RowShared S;
  const int r = blockIdx.x;
  const int s = (r >= B) + (r >= 2 * B);   // heavy s0 rows dispatched first
  const int b = r - s * B;
  float* part = g_part + (size_t)r * 4;
  if (s == 0)      row_impl<6400>(p0, b, part, S);
  else if (s == 1) row_impl<1600>(p1, b, part, S);
  else             row_impl<400>(p2, b, part, S);

  if (threadIdx.x == 0) {
    __threadfence();                          // release part[] stores
    const unsigned old = atomicAdd(done, 1u); // single-word ticket
    S.sh_flag = (old == (unsigned)(R - 1)) ? 1 : 0;
  }
  __syncthreads();
  if (S.sh_flag) {
    __threadfence();                          // acquire side
    const int t = threadIdx.x;
    float o = 0.f, c = 0.f, l = 0.f;
    for (int i = t; i < R; i += BLK) {
      o += g_part[i * 4 + 0];
      c += g_part[i * 4 + 1];
      l += g_part[i * 4 + 2];
    }
    o = blockSum(o, S.fscr);
    c = blockSum(c, S.fscr);
    l = blockSum(l, S.fscr);
    if (t == 0) {
      out[0] = (o + c + l) * invB;
      out[1] = o * invB;
      out[2] = c * invB;
      out[3] = l * invB;
    }
  }
}

extern "C" void kernel_launch(void* const* d_in, const int* in_sizes, int n_in,
                              void* d_out, int out_size, void* d_ws, size_t ws_size,
                              hipStream_t stream) {
  (void)n_in; (void)out_size; (void)ws_size;

  const int HW0 = 80 * 80, HW1 = 40 * 40, HW2 = 20 * 20;
  const int B = in_sizes[0] / (NA * KCH * HW0);
  const int R = 3 * B;
  const float invB = 1.f / (float)B;

  ScaleParams p0{(const float*)d_in[0],  (const float*)d_in[1],
                 (const int*)d_in[2],    (const uint8_t*)d_in[3],
                 (const uint8_t*)d_in[4], HW0};
  ScaleParams p1{(const float*)d_in[5],  (const float*)d_in[6],
                 (const int*)d_in[7],    (const uint8_t*)d_in[8],
                 (const uint8_t*)d_in[9], HW1};
  ScaleParams p2{(const float*)d_in[10], (const float*)d_in[11],
                 (const int*)d_in[12],   (const uint8_t*)d_in[13],
                 (const uint8_t*)d_in[14], HW2};

  float* out = (float*)d_out;
  unsigned* done = (unsigned*)d_ws;
  float* g_part = (float*)((char*)d_ws + 256);   // R*4 floats, plain stores

  k_zero<<<1, 64, 0, stream>>>(done);
  k_row<<<R, BLK, 0, stream>>>(p0, p1, p2, B, R, invB, g_part, done, out);
}